// Round 3
// baseline (468.053 us; speedup 1.0000x reference)
//
#include <hip/hip_runtime.h>
#include <hip/hip_bf16.h>

// Problem constants
#define NN 8192
#define FF 128
#define DD 128
#define HH 2
#define ALPHA 0.3f
#define MAXNNZ 1024

// ---------------------------------------------------------------------------
// Kernel A: c1[h,f] = sum_d Wmap[h,f,d]*a1_w[h,d]; c2 likewise with a2_w.
// ---------------------------------------------------------------------------
__global__ __launch_bounds__(256) void c_kernel(
    const float* __restrict__ Wmap, const float* __restrict__ a1w,
    const float* __restrict__ a2w, float* __restrict__ c1, float* __restrict__ c2) {
  int t = threadIdx.x;              // 0..255
  int h = t >> 7, f = t & 127;
  const float* wrow = Wmap + ((size_t)h * FF + f) * DD;
  const float* a1 = a1w + h * DD;
  const float* a2 = a2w + h * DD;
  float s1 = 0.f, s2 = 0.f;
  #pragma unroll 8
  for (int d = 0; d < DD; d++) {
    float w = wrow[d];
    s1 += w * a1[d];
    s2 += w * a2[d];
  }
  c1[t] = s1;
  c2[t] = s2;
}

// ---------------------------------------------------------------------------
// Kernel B: sa1[h,n] = x[n,:].c1[h,:] + a1_b[h]; sa2 likewise.
// One block (128 threads) per node; 4 simultaneous reductions.
// ---------------------------------------------------------------------------
__global__ __launch_bounds__(128) void sa_kernel(
    const float* __restrict__ x, const float* __restrict__ c1,
    const float* __restrict__ c2, const float* __restrict__ a1b,
    const float* __restrict__ a2b, float* __restrict__ sa1, float* __restrict__ sa2) {
  int n = blockIdx.x;
  int f = threadIdx.x;
  float xv = x[(size_t)n * FF + f];
  float p00 = xv * c1[f];         // head 0, score 1
  float p01 = xv * c1[FF + f];    // head 1, score 1
  float p10 = xv * c2[f];         // head 0, score 2
  float p11 = xv * c2[FF + f];    // head 1, score 2
  #pragma unroll
  for (int o = 32; o > 0; o >>= 1) {
    p00 += __shfl_down(p00, o);
    p01 += __shfl_down(p01, o);
    p10 += __shfl_down(p10, o);
    p11 += __shfl_down(p11, o);
  }
  __shared__ float part[2][4];
  int w = f >> 6;
  if ((f & 63) == 0) {
    part[w][0] = p00; part[w][1] = p01; part[w][2] = p10; part[w][3] = p11;
  }
  __syncthreads();
  if (f == 0) {
    sa1[n]      = part[0][0] + part[1][0] + a1b[0];
    sa1[NN + n] = part[0][1] + part[1][1] + a1b[1];
    sa2[n]      = part[0][2] + part[1][2] + a2b[0];
    sa2[NN + n] = part[0][3] + part[1][3] + a2b[1];
  }
}

// ---------------------------------------------------------------------------
// Kernel C: value[h] = x @ kernel[h]  (fp32 accumulate).
//   Outputs: value_bf (bf16, for the sparse gather — 4 MB, L2-resident)
//            colsum   (fp32 column sums, fused epilogue, atomicAdd)
// ---------------------------------------------------------------------------
__global__ __launch_bounds__(256) void value_gemm(
    const float* __restrict__ x, const float* __restrict__ kern,
    unsigned short* __restrict__ value_bf, float* __restrict__ colsum) {
  int h = blockIdx.y;
  int row0 = blockIdx.x * 32;
  __shared__ float Bl[64 * 128];    // 32 KB
  __shared__ float Al[32 * 129];    // 16.5 KB
  const float4* Bg4 = (const float4*)(kern + (size_t)h * FF * DD);
  const float4* Ag4 = (const float4*)(x + (size_t)row0 * FF);
  float4* Bl4 = (float4*)Bl;
  int tid = threadIdx.x;

  // stage A: 32 rows x 128 cols = 1024 float4
  #pragma unroll
  for (int q = 0; q < 4; q++) {
    int idx = q * 256 + tid;        // 0..1023
    int r = idx >> 5, c4 = idx & 31;
    float4 g = Ag4[idx];
    Al[r * 129 + c4 * 4 + 0] = g.x;
    Al[r * 129 + c4 * 4 + 1] = g.y;
    Al[r * 129 + c4 * 4 + 2] = g.z;
    Al[r * 129 + c4 * 4 + 3] = g.w;
  }

  int cg = tid & 31;                // column group: cols cg*4..cg*4+3
  int rg = tid >> 5;                // 0..7; rows rg, rg+8, rg+16, rg+24
  float4 acc[4];
  #pragma unroll
  for (int m = 0; m < 4; m++) acc[m] = make_float4(0.f, 0.f, 0.f, 0.f);

  for (int kp = 0; kp < 2; kp++) {
    __syncthreads();
    #pragma unroll
    for (int q = 0; q < 8; q++)
      Bl4[q * 256 + tid] = Bg4[kp * 2048 + q * 256 + tid];
    __syncthreads();
    for (int k2 = 0; k2 < 64; k2++) {
      int k = kp * 64 + k2;
      float4 bv = *(const float4*)&Bl[k2 * 128 + cg * 4];
      #pragma unroll
      for (int m = 0; m < 4; m++) {
        float av = Al[(rg + m * 8) * 129 + k];
        acc[m].x += av * bv.x;
        acc[m].y += av * bv.y;
        acc[m].z += av * bv.z;
        acc[m].w += av * bv.w;
      }
    }
  }

  // store bf16 value rows
  #pragma unroll
  for (int m = 0; m < 4; m++) {
    int r = row0 + rg + m * 8;
    ushort4 pk;
    __hip_bfloat16 b0 = __float2bfloat16(acc[m].x);
    __hip_bfloat16 b1 = __float2bfloat16(acc[m].y);
    __hip_bfloat16 b2 = __float2bfloat16(acc[m].z);
    __hip_bfloat16 b3 = __float2bfloat16(acc[m].w);
    pk.x = *(unsigned short*)&b0;
    pk.y = *(unsigned short*)&b1;
    pk.z = *(unsigned short*)&b2;
    pk.w = *(unsigned short*)&b3;
    *(ushort4*)&value_bf[((size_t)h * NN + r) * DD + cg * 4] = pk;
  }

  // fused colsum epilogue: per-thread column partials -> LDS -> atomicAdd
  float4 cp;
  cp.x = acc[0].x + acc[1].x + acc[2].x + acc[3].x;
  cp.y = acc[0].y + acc[1].y + acc[2].y + acc[3].y;
  cp.z = acc[0].z + acc[1].z + acc[2].z + acc[3].z;
  cp.w = acc[0].w + acc[1].w + acc[2].w + acc[3].w;
  __syncthreads();                  // done reading Al; reuse as colred[8][128]
  float* colred = Al;
  *(float4*)&colred[rg * 128 + cg * 4] = cp;
  __syncthreads();
  if (rg == 0) {                    // tid 0..31, each owns 4 columns
    #pragma unroll
    for (int c = 0; c < 4; c++) {
      int col = cg * 4 + c;
      float s = 0.f;
      #pragma unroll
      for (int rr = 0; rr < 8; rr++) s += colred[rr * 128 + col];
      atomicAdd(&colsum[h * DD + col], s);
    }
  }
}

// ---------------------------------------------------------------------------
// Kernel E: main sparse-attention kernel. One block (256 thr) per row i.
//   Phase A : float4-scan adj row; ballot-compact nonzero cols into LDS.
//   Phase B1: one thread per edge: em1 = exp(leaky(s)) - 1 (both heads).
//   Phase B2: t -> (h,d). acc += em1[k]*value_bf[h,j,d]; mean over heads.
// ---------------------------------------------------------------------------
__global__ __launch_bounds__(256) void gat_main(
    const float* __restrict__ adj, const float* __restrict__ sa1,
    const float* __restrict__ sa2, const unsigned short* __restrict__ value_bf,
    const float* __restrict__ colsum, const float* __restrict__ bias,
    float* __restrict__ out) {
  int i = blockIdx.x;
  __shared__ int idxbuf[MAXNNZ];
  __shared__ float em1buf[HH][MAXNNZ];
  __shared__ int cnt;
  __shared__ float sume_sh[HH];
  __shared__ float wred[4][HH];
  __shared__ float contrib[256];
  int t = threadIdx.x;
  int lane = t & 63;
  if (t == 0) cnt = 0;
  __syncthreads();

  // ---- Phase A: ballot-compact adjacency row ----
  const float4* arow = (const float4*)(adj + (size_t)i * NN);
  #pragma unroll
  for (int q = 0; q < 8; q++) {
    int f4 = q * 256 + t;           // 0..2047
    float4 a = arow[f4];
    int j0 = f4 * 4;
    float av[4] = {a.x, a.y, a.z, a.w};
    #pragma unroll
    for (int c = 0; c < 4; c++) {
      bool nz = (av[c] != 0.f);
      unsigned long long m = __ballot(nz);
      int tot = __popcll(m);
      int base = 0;
      if (lane == 0 && tot) base = atomicAdd(&cnt, tot);
      base = __shfl(base, 0);
      if (nz) {
        int p = base + __popcll(m & ((1ull << lane) - 1ull));
        if (p < MAXNNZ) idxbuf[p] = j0 + c;
      }
    }
  }
  __syncthreads();
  int count = min(cnt, MAXNNZ);

  // ---- Phase B1: per-edge scores ----
  float s10 = sa1[i];               // head 0 row score
  float s11 = sa1[NN + i];          // head 1 row score
  float l0 = 0.f, l1 = 0.f;         // partial sums of (e-1)
  for (int k = t; k < count; k += 256) {
    int j = idxbuf[k];
    float w0 = s10 + sa2[j];
    float w1 = s11 + sa2[NN + j];
    w0 = (w0 >= 0.f) ? w0 : ALPHA * w0;
    w1 = (w1 >= 0.f) ? w1 : ALPHA * w1;
    float e0 = __expf(w0) - 1.f;
    float e1 = __expf(w1) - 1.f;
    em1buf[0][k] = e0;
    em1buf[1][k] = e1;
    l0 += e0;
    l1 += e1;
  }
  #pragma unroll
  for (int o = 32; o > 0; o >>= 1) {
    l0 += __shfl_down(l0, o);
    l1 += __shfl_down(l1, o);
  }
  int wid = t >> 6;
  if (lane == 0) { wred[wid][0] = l0; wred[wid][1] = l1; }
  __syncthreads();
  if (t == 0) {
    sume_sh[0] = wred[0][0] + wred[1][0] + wred[2][0] + wred[3][0];
    sume_sh[1] = wred[0][1] + wred[1][1] + wred[2][1] + wred[3][1];
  }
  __syncthreads();

  // ---- Phase B2: weighted gather of bf16 value rows ----
  int h = t >> 7, d = t & 127;
  const unsigned short* val = value_bf + (size_t)h * NN * DD + d;
  const float* eb = em1buf[h];
  float acc = 0.f;
  #pragma unroll 4
  for (int k = 0; k < count; k++) {
    int j = idxbuf[k];
    unsigned short u = val[(size_t)j * DD];
    __hip_bfloat16 bv = *(__hip_bfloat16*)&u;
    acc += eb[k] * __bfloat162float(bv);
  }
  // denom = (N - count) + sum(e) = N + sum(e-1)
  float denom = (float)NN + sume_sh[h];
  float r = (colsum[h * DD + d] + acc) / denom +
            bias[((size_t)h * NN + i) * DD + d];
  contrib[t] = r;
  __syncthreads();
  if (t < 64) {                     // one wave writes 128 floats as float2
    float2 o2;
    o2.x = 0.5f * (contrib[2 * t]     + contrib[2 * t + 128]);
    o2.y = 0.5f * (contrib[2 * t + 1] + contrib[2 * t + 129]);
    *(float2*)&out[(size_t)i * DD + 2 * t] = o2;
  }
}

// ---------------------------------------------------------------------------
// Launch
// ---------------------------------------------------------------------------
extern "C" void kernel_launch(void* const* d_in, const int* in_sizes, int n_in,
                              void* d_out, int out_size, void* d_ws, size_t ws_size,
                              hipStream_t stream) {
  const float* x    = (const float*)d_in[0];
  const float* adj  = (const float*)d_in[1];
  const float* Wmap = (const float*)d_in[2];
  const float* a1w  = (const float*)d_in[3];
  const float* a1b  = (const float*)d_in[4];
  const float* a2w  = (const float*)d_in[5];
  const float* a2b  = (const float*)d_in[6];
  const float* kern = (const float*)d_in[7];
  const float* bias = (const float*)d_in[8];
  float* out = (float*)d_out;
  float* ws  = (float*)d_ws;

  // workspace layout (floats)
  float* c1     = ws;            // 256
  float* c2     = ws + 256;      // 256
  float* sa1    = ws + 512;      // 16384
  float* sa2    = ws + 16896;    // 16384
  float* colsum = ws + 33280;    // 256
  unsigned short* value_bf = (unsigned short*)(ws + 33536);  // 2*8192*128 bf16

  hipMemsetAsync(colsum, 0, HH * DD * sizeof(float), stream);
  c_kernel<<<1, 256, 0, stream>>>(Wmap, a1w, a2w, c1, c2);
  sa_kernel<<<NN, 128, 0, stream>>>(x, c1, c2, a1b, a2b, sa1, sa2);
  value_gemm<<<dim3(NN / 32, HH), 256, 0, stream>>>(x, kern, value_bf, colsum);
  gat_main<<<NN, 256, 0, stream>>>(adj, sa1, sa2, value_bf, colsum, bias, out);
}

// Round 5
// 460.640 us; speedup vs baseline: 1.0161x; 1.0161x over previous
//
#include <hip/hip_runtime.h>
#include <hip/hip_bf16.h>

// Problem constants
#define NN 8192
#define FF 128
#define DD 128
#define HH 2
#define ALPHA 0.3f
#define MAXNNZ 1024

typedef float vfloat4 __attribute__((ext_vector_type(4)));

// ---------------------------------------------------------------------------
// Kernel P (fused prep): grid (256, H), 256 threads.
// Block (rb, h) with rows r0 = rb*32 .. +31:
//   1. stage x rows into LDS (Al), compute cvec[2][128] = Wmap[h]@{a1w,a2w}
//   2. sa1/sa2 for its 32 rows (head h) from Al . cvec
//   3. value[h] tile = Al @ kernel[h]  (fp32 acc, bf16 store)
//   4. fused colsum partial -> atomicAdd
// ---------------------------------------------------------------------------
__global__ __launch_bounds__(256) void prep_kernel(
    const float* __restrict__ x, const float* __restrict__ kern,
    const float* __restrict__ Wmap, const float* __restrict__ a1w,
    const float* __restrict__ a2w, const float* __restrict__ a1b,
    const float* __restrict__ a2b, unsigned short* __restrict__ value_bf,
    float* __restrict__ colsum, float* __restrict__ sa1, float* __restrict__ sa2) {
  int h = blockIdx.y;
  int row0 = blockIdx.x * 32;
  __shared__ float Bl[64 * 128];    // 32 KB
  __shared__ float Al[32 * 129];    // 16.5 KB
  __shared__ float cvec[2][128];    // 1 KB
  const float4* Bg4 = (const float4*)(kern + (size_t)h * FF * DD);
  const float4* Ag4 = (const float4*)(x + (size_t)row0 * FF);
  float4* Bl4 = (float4*)Bl;
  int tid = threadIdx.x;

  // ---- stage A: 32 rows x 128 cols = 1024 float4 ----
  #pragma unroll
  for (int q = 0; q < 4; q++) {
    int idx = q * 256 + tid;        // 0..1023
    int r = idx >> 5, c4 = idx & 31;
    float4 g = Ag4[idx];
    Al[r * 129 + c4 * 4 + 0] = g.x;
    Al[r * 129 + c4 * 4 + 1] = g.y;
    Al[r * 129 + c4 * 4 + 2] = g.z;
    Al[r * 129 + c4 * 4 + 3] = g.w;
  }

  // ---- c vectors: thread t -> (which = t>>7, f = t&127) ----
  {
    int which = tid >> 7, f = tid & 127;
    const float4* w4 = (const float4*)(Wmap + ((size_t)h * FF + f) * DD);
    const float4* av4 = (const float4*)((which ? a2w : a1w) + (size_t)h * DD);
    float s = 0.f;
    #pragma unroll 8
    for (int dq = 0; dq < 32; dq++) {
      float4 w = w4[dq];
      float4 a = av4[dq];
      s += w.x * a.x + w.y * a.y + w.z * a.z + w.w * a.w;
    }
    cvec[which][f] = s;
  }
  __syncthreads();

  // ---- sa for this block's 32 rows, head h (threads 0..63) ----
  if (tid < 64) {
    int r = tid & 31, type = tid >> 5;
    const float* cv = cvec[type];
    float s = 0.f;
    #pragma unroll 8
    for (int f = 0; f < 128; f++) s += Al[r * 129 + f] * cv[f];
    float b = type ? a2b[h] : a1b[h];
    float* dst = type ? sa2 : sa1;
    dst[(size_t)h * NN + row0 + r] = s + b;
  }

  // ---- GEMM: thread tile 4 rows x 4 cols ----
  int cg = tid & 31;                // cols cg*4..cg*4+3
  int rg = tid >> 5;                // rows rg, rg+8, rg+16, rg+24
  float4 acc[4];
  #pragma unroll
  for (int m = 0; m < 4; m++) acc[m] = make_float4(0.f, 0.f, 0.f, 0.f);

  for (int kp = 0; kp < 2; kp++) {
    __syncthreads();
    #pragma unroll
    for (int q = 0; q < 8; q++)
      Bl4[q * 256 + tid] = Bg4[kp * 2048 + q * 256 + tid];
    __syncthreads();
    for (int k2 = 0; k2 < 64; k2++) {
      int k = kp * 64 + k2;
      float4 bv = *(const float4*)&Bl[k2 * 128 + cg * 4];
      #pragma unroll
      for (int m = 0; m < 4; m++) {
        float av = Al[(rg + m * 8) * 129 + k];
        acc[m].x += av * bv.x;
        acc[m].y += av * bv.y;
        acc[m].z += av * bv.z;
        acc[m].w += av * bv.w;
      }
    }
  }

  // ---- store bf16 value rows ----
  #pragma unroll
  for (int m = 0; m < 4; m++) {
    int r = row0 + rg + m * 8;
    ushort4 pk;
    __hip_bfloat16 b0 = __float2bfloat16(acc[m].x);
    __hip_bfloat16 b1 = __float2bfloat16(acc[m].y);
    __hip_bfloat16 b2 = __float2bfloat16(acc[m].z);
    __hip_bfloat16 b3 = __float2bfloat16(acc[m].w);
    pk.x = *(unsigned short*)&b0;
    pk.y = *(unsigned short*)&b1;
    pk.z = *(unsigned short*)&b2;
    pk.w = *(unsigned short*)&b3;
    *(ushort4*)&value_bf[((size_t)h * NN + r) * DD + cg * 4] = pk;
  }

  // ---- fused colsum: per-thread column partials -> LDS -> atomicAdd ----
  float4 cp;
  cp.x = acc[0].x + acc[1].x + acc[2].x + acc[3].x;
  cp.y = acc[0].y + acc[1].y + acc[2].y + acc[3].y;
  cp.z = acc[0].z + acc[1].z + acc[2].z + acc[3].z;
  cp.w = acc[0].w + acc[1].w + acc[2].w + acc[3].w;
  __syncthreads();                  // done reading Al; reuse as colred[8][128]
  float* colred = Al;
  *(float4*)&colred[rg * 128 + cg * 4] = cp;
  __syncthreads();
  if (rg == 0) {                    // tid 0..31, each owns 4 columns
    #pragma unroll
    for (int c = 0; c < 4; c++) {
      int col = cg * 4 + c;
      float s = 0.f;
      #pragma unroll
      for (int rr = 0; rr < 8; rr++) s += colred[rr * 128 + col];
      atomicAdd(&colsum[h * DD + col], s);
    }
  }
}

// ---------------------------------------------------------------------------
// Kernel E: main sparse-attention kernel. One block (256 thr) per row i.
//   Phase A : nt-load float4 scan of adj row; ballot-compact cols into LDS.
//   Phase B1: one thread per edge: em1 = exp(leaky(s)) - 1 (both heads).
//   Phase B2: t -> (h,d). acc += em1[k]*value_bf[h,j,d]; mean over heads.
// ---------------------------------------------------------------------------
__global__ __launch_bounds__(256) void gat_main(
    const float* __restrict__ adj, const float* __restrict__ sa1,
    const float* __restrict__ sa2, const unsigned short* __restrict__ value_bf,
    const float* __restrict__ colsum, const float* __restrict__ bias,
    float* __restrict__ out) {
  int i = blockIdx.x;
  __shared__ int idxbuf[MAXNNZ];
  __shared__ float em1buf[HH][MAXNNZ];
  __shared__ int cnt;
  __shared__ float sume_sh[HH];
  __shared__ float wred[4][HH];
  __shared__ float contrib[256];
  int t = threadIdx.x;
  int lane = t & 63;
  if (t == 0) cnt = 0;
  __syncthreads();

  // ---- Phase A: ballot-compact adjacency row (nt loads: adj is stream-once,
  //      keep it from evicting value_bf out of L2) ----
  const vfloat4* arow = (const vfloat4*)(adj + (size_t)i * NN);
  #pragma unroll
  for (int q = 0; q < 8; q++) {
    int f4 = q * 256 + t;           // 0..2047
    vfloat4 a = __builtin_nontemporal_load(&arow[f4]);
    int j0 = f4 * 4;
    #pragma unroll
    for (int c = 0; c < 4; c++) {
      bool nz = (a[c] != 0.f);
      unsigned long long m = __ballot(nz);
      int tot = __popcll(m);
      int base = 0;
      if (lane == 0 && tot) base = atomicAdd(&cnt, tot);
      base = __shfl(base, 0);
      if (nz) {
        int p = base + __popcll(m & ((1ull << lane) - 1ull));
        if (p < MAXNNZ) idxbuf[p] = j0 + c;
      }
    }
  }
  __syncthreads();
  int count = min(cnt, MAXNNZ);

  // ---- Phase B1: per-edge scores ----
  float s10 = sa1[i];               // head 0 row score
  float s11 = sa1[NN + i];          // head 1 row score
  float l0 = 0.f, l1 = 0.f;         // partial sums of (e-1)
  for (int k = t; k < count; k += 256) {
    int j = idxbuf[k];
    float w0 = s10 + sa2[j];
    float w1 = s11 + sa2[NN + j];
    w0 = (w0 >= 0.f) ? w0 : ALPHA * w0;
    w1 = (w1 >= 0.f) ? w1 : ALPHA * w1;
    float e0 = __expf(w0) - 1.f;
    float e1 = __expf(w1) - 1.f;
    em1buf[0][k] = e0;
    em1buf[1][k] = e1;
    l0 += e0;
    l1 += e1;
  }
  #pragma unroll
  for (int o = 32; o > 0; o >>= 1) {
    l0 += __shfl_down(l0, o);
    l1 += __shfl_down(l1, o);
  }
  int wid = t >> 6;
  if (lane == 0) { wred[wid][0] = l0; wred[wid][1] = l1; }
  __syncthreads();
  if (t == 0) {
    sume_sh[0] = wred[0][0] + wred[1][0] + wred[2][0] + wred[3][0];
    sume_sh[1] = wred[0][1] + wred[1][1] + wred[2][1] + wred[3][1];
  }
  __syncthreads();

  // ---- Phase B2: weighted gather of bf16 value rows ----
  int h = t >> 7, d = t & 127;
  const unsigned short* val = value_bf + (size_t)h * NN * DD + d;
  const float* eb = em1buf[h];
  float acc = 0.f;
  #pragma unroll 4
  for (int k = 0; k < count; k++) {
    int j = idxbuf[k];
    unsigned short u = val[(size_t)j * DD];
    __hip_bfloat16 bv = *(__hip_bfloat16*)&u;
    acc += eb[k] * __bfloat162float(bv);
  }
  // denom = (N - count) + sum(e) = N + sum(e-1)
  float denom = (float)NN + sume_sh[h];
  float bb = __builtin_nontemporal_load(&bias[((size_t)h * NN + i) * DD + d]);
  float r = (colsum[h * DD + d] + acc) / denom + bb;
  contrib[t] = r;
  __syncthreads();
  if (t < 64) {                     // one wave writes 128 floats as float2
    float2 o2;
    o2.x = 0.5f * (contrib[2 * t]     + contrib[2 * t + 128]);
    o2.y = 0.5f * (contrib[2 * t + 1] + contrib[2 * t + 129]);
    *(float2*)&out[(size_t)i * DD + 2 * t] = o2;
  }
}

// ---------------------------------------------------------------------------
// Launch
// ---------------------------------------------------------------------------
extern "C" void kernel_launch(void* const* d_in, const int* in_sizes, int n_in,
                              void* d_out, int out_size, void* d_ws, size_t ws_size,
                              hipStream_t stream) {
  const float* x    = (const float*)d_in[0];
  const float* adj  = (const float*)d_in[1];
  const float* Wmap = (const float*)d_in[2];
  const float* a1w  = (const float*)d_in[3];
  const float* a1b  = (const float*)d_in[4];
  const float* a2w  = (const float*)d_in[5];
  const float* a2b  = (const float*)d_in[6];
  const float* kern = (const float*)d_in[7];
  const float* bias = (const float*)d_in[8];
  float* out = (float*)d_out;
  float* ws  = (float*)d_ws;

  // workspace layout (floats)
  float* sa1    = ws;            // 16384
  float* sa2    = ws + 16384;    // 16384
  float* colsum = ws + 32768;    // 256
  unsigned short* value_bf = (unsigned short*)(ws + 33024);  // 2*8192*128 bf16

  (void)hipMemsetAsync(colsum, 0, HH * DD * sizeof(float), stream);
  prep_kernel<<<dim3(NN / 32, HH), 256, 0, stream>>>(
      x, kern, Wmap, a1w, a2w, a1b, a2b, value_bf, colsum, sa1, sa2);
  gat_main<<<NN, 256, 0, stream>>>(adj, sa1, sa2, value_bf, colsum, bias, out);
}